// Round 1
// baseline (565.445 us; speedup 1.0000x reference)
//
#include <hip/hip_runtime.h>
#include <cstdint>

#define DD 128
#define LL 64

// ---------------- degree count ----------------
__global__ __launch_bounds__(256) void k_deg(const int* __restrict__ dst, int* __restrict__ deg, int E) {
    int e = blockIdx.x * 256 + threadIdx.x;
    if (e < E) atomicAdd(&deg[dst[e]], 1);
}

// ---------------- y = x@W1_rel^T, z = x@W1_root^T ----------------
// 256 threads = 4 groups x 64 lanes; block handles 32 nodes (8 per group).
// W staged in LDS with XOR swizzle so 64 lanes reading different rows at the
// same column hit all 32 banks (guide G4 / T2 pattern).
__global__ __launch_bounds__(256) void k1_gemm(const float* __restrict__ x,
        const float* __restrict__ Wrel, const float* __restrict__ Wroot,
        float* __restrict__ y, float* __restrict__ z, int n)
{
    __shared__ __align__(16) float wrel_s[LL * DD];
    __shared__ __align__(16) float wroot_s[LL * DD];
    __shared__ __align__(16) float xs[4][DD];
    int tid = threadIdx.x;
    for (int idx = tid; idx < LL * DD; idx += 256) {
        int o = idx >> 7, k = idx & 127;
        int sw = (o << 7) | (k ^ ((o & 7) << 2));  // store (o,k) at column k^((o&7)<<2)
        wrel_s[sw]  = Wrel[idx];
        wroot_s[sw] = Wroot[idx];
    }
    __syncthreads();
    int group = tid >> 6, lane = tid & 63;
    int base = blockIdx.x * 32 + group * 8;
    int swz = (lane & 7) << 2;
    for (int r = 0; r < 8; ++r) {
        int i = base + r;
        if (i < n) {
            xs[group][lane]      = x[(size_t)i * DD + lane];
            xs[group][lane + 64] = x[(size_t)i * DD + lane + 64];
        }
        __syncthreads();
        if (i < n) {
            float accY = 0.f, accZ = 0.f;
            #pragma unroll
            for (int k = 0; k < DD; k += 4) {
                int kk = k ^ swz;  // k,swz multiples of 4 -> float4 at kk holds cols k..k+3
                float4 wr = *(const float4*)&wrel_s[(lane << 7) + kk];
                float4 wo = *(const float4*)&wroot_s[(lane << 7) + kk];
                float4 xv = *(const float4*)&xs[group][k];
                accY += wr.x * xv.x + wr.y * xv.y + wr.z * xv.z + wr.w * xv.w;
                accZ += wo.x * xv.x + wo.y * xv.y + wo.z * xv.z + wo.w * xv.w;
            }
            y[(size_t)i * LL + lane] = accY;
            z[(size_t)i * LL + lane] = accZ;
        }
        __syncthreads();
    }
}

// ---------------- scan (3-phase) over deg -> rowptr, cursor ----------------
__global__ __launch_bounds__(1024) void p1_blocksum(const int* __restrict__ deg, int* __restrict__ blocksum, int n) {
    __shared__ int sc[1024];
    int i = blockIdx.x * 1024 + threadIdx.x;
    sc[threadIdx.x] = (i < n) ? deg[i] : 0;
    __syncthreads();
    for (int off = 512; off > 0; off >>= 1) {
        if (threadIdx.x < off) sc[threadIdx.x] += sc[threadIdx.x + off];
        __syncthreads();
    }
    if (threadIdx.x == 0) blocksum[blockIdx.x] = sc[0];
}

__global__ void p2_scan_blocks(const int* __restrict__ blocksum, int* __restrict__ blockoff, int nb) {
    if (threadIdx.x == 0) {
        int run = 0;
        for (int j = 0; j < nb; ++j) { blockoff[j] = run; run += blocksum[j]; }
    }
}

__global__ __launch_bounds__(1024) void p3_scan(const int* __restrict__ deg, const int* __restrict__ blockoff,
        int* __restrict__ rowptr, int* __restrict__ cursor, int n)
{
    __shared__ int sc[1024];
    int i = blockIdx.x * 1024 + threadIdx.x;
    int v = (i < n) ? deg[i] : 0;
    sc[threadIdx.x] = v;
    __syncthreads();
    for (int off = 1; off < 1024; off <<= 1) {
        int add = (threadIdx.x >= off) ? sc[threadIdx.x - off] : 0;
        __syncthreads();
        sc[threadIdx.x] += add;
        __syncthreads();
    }
    if (i < n) {
        int incl = sc[threadIdx.x] + blockoff[blockIdx.x];
        rowptr[i + 1] = incl;
        cursor[i] = incl - v;
        if (i == 0) rowptr[0] = 0;
    }
}

// ---------------- CSR scatter ----------------
__global__ __launch_bounds__(256) void k2c_scatter(const int* __restrict__ src, const int* __restrict__ dst,
        int* __restrict__ cursor, int* __restrict__ csr, int E)
{
    int e = blockIdx.x * 256 + threadIdx.x;
    if (e < E) {
        int d = dst[e];
        int pos = atomicAdd(&cursor[d], 1);
        csr[pos] = src[e];
    }
}

// ---------------- layer-1 aggregate + h + s,t (one wave per node) ----------------
__global__ __launch_bounds__(256) void k3_agg(const float* __restrict__ y, const float* __restrict__ z,
        const int* __restrict__ rowptr, const int* __restrict__ csr,
        const float* __restrict__ b1, const float* __restrict__ w2rel, const float* __restrict__ w2root,
        float* __restrict__ s, float* __restrict__ t, int n)
{
    int wave = threadIdx.x >> 6, lane = threadIdx.x & 63;
    int i = blockIdx.x * 4 + wave;
    if (i >= n) return;
    int st = rowptr[i], en = rowptr[i + 1];
    float acc = 0.f;
    for (int e = st; e < en; ++e) {
        int sj = csr[e];
        acc += y[(size_t)sj * LL + lane];   // coalesced 256B row gather
    }
    float h = acc + z[(size_t)i * LL + lane] + b1[lane];
    h = h > 0.f ? h : 0.2f * h;             // leaky_relu(0.2)
    float sv = h * w2rel[lane];
    float tv = h * w2root[lane];
    #pragma unroll
    for (int o = 32; o >= 1; o >>= 1) {
        sv += __shfl_xor(sv, o, 64);
        tv += __shfl_xor(tv, o, 64);
    }
    if (lane == 0) { s[i] = sv; t[i] = tv; }
}

// ---------------- gate logits ----------------
__global__ __launch_bounds__(256) void k5_gate(const float* __restrict__ s, const float* __restrict__ t,
        const int* __restrict__ rowptr, const int* __restrict__ csr, const float* __restrict__ b2,
        float* __restrict__ g, int n)
{
    int i = blockIdx.x * 256 + threadIdx.x;
    if (i >= n) return;
    float acc = b2[0] + t[i];
    int st = rowptr[i], en = rowptr[i + 1];
    for (int e = st; e < en; ++e) acc += s[csr[e]];
    g[i] = acc;
}

// ---------------- softmax reductions ----------------
__global__ __launch_bounds__(256) void k6_max(const float* __restrict__ g, float* __restrict__ pmax, int n) {
    __shared__ float sc[256];
    float m = -3.402823466e38f;
    for (int i = blockIdx.x * 256 + threadIdx.x; i < n; i += gridDim.x * 256)
        m = fmaxf(m, g[i]);
    sc[threadIdx.x] = m;
    __syncthreads();
    for (int off = 128; off > 0; off >>= 1) {
        if (threadIdx.x < off) sc[threadIdx.x] = fmaxf(sc[threadIdx.x], sc[threadIdx.x + off]);
        __syncthreads();
    }
    if (threadIdx.x == 0) pmax[blockIdx.x] = sc[0];
}

__global__ __launch_bounds__(256) void k6_maxfin(const float* __restrict__ pmax, float* __restrict__ scalars) {
    __shared__ float sc[256];
    sc[threadIdx.x] = pmax[threadIdx.x];
    __syncthreads();
    for (int off = 128; off > 0; off >>= 1) {
        if (threadIdx.x < off) sc[threadIdx.x] = fmaxf(sc[threadIdx.x], sc[threadIdx.x + off]);
        __syncthreads();
    }
    if (threadIdx.x == 0) scalars[0] = sc[0];
}

__global__ __launch_bounds__(256) void k6_sumexp(const float* __restrict__ g, float* __restrict__ scalars, int n) {
    __shared__ float sc[256];
    float m = scalars[0];
    float local = 0.f;
    for (int i = blockIdx.x * 256 + threadIdx.x; i < n; i += gridDim.x * 256)
        local += expf(g[i] - m);
    sc[threadIdx.x] = local;
    __syncthreads();
    for (int off = 128; off > 0; off >>= 1) {
        if (threadIdx.x < off) sc[threadIdx.x] += sc[threadIdx.x + off];
        __syncthreads();
    }
    if (threadIdx.x == 0) atomicAdd(&scalars[1], sc[0]);
}

// ---------------- out[d] = sum_i softmax(g)_i * x[i,d] ----------------
__global__ __launch_bounds__(256) void k6_out(const float* __restrict__ x, const float* __restrict__ g,
        const float* __restrict__ scalars, float* __restrict__ out, int n)
{
    __shared__ float acc_s[4][DD];
    int wave = threadIdx.x >> 6, lane = threadIdx.x & 63;
    float m = scalars[0];
    float invZ = 1.0f / scalars[1];
    float a0 = 0.f, a1 = 0.f;
    int gw = blockIdx.x * 4 + wave;
    int nw = gridDim.x * 4;
    for (int i = gw; i < n; i += nw) {
        float w = expf(g[i] - m) * invZ;
        a0 += w * x[(size_t)i * DD + lane];
        a1 += w * x[(size_t)i * DD + 64 + lane];
    }
    acc_s[wave][lane] = a0;
    acc_s[wave][lane + 64] = a1;
    __syncthreads();
    if (wave == 0) {
        float v0 = acc_s[0][lane] + acc_s[1][lane] + acc_s[2][lane] + acc_s[3][lane];
        float v1 = acc_s[0][lane + 64] + acc_s[1][lane + 64] + acc_s[2][lane + 64] + acc_s[3][lane + 64];
        atomicAdd(&out[lane], v0);
        atomicAdd(&out[lane + 64], v1);
    }
}

extern "C" void kernel_launch(void* const* d_in, const int* in_sizes, int n_in,
                              void* d_out, int out_size, void* d_ws, size_t ws_size,
                              hipStream_t stream)
{
    const float* x      = (const float*)d_in[0];
    const int*   eidx   = (const int*)d_in[1];
    const float* W1rel  = (const float*)d_in[2];
    const float* b1     = (const float*)d_in[3];
    const float* W1root = (const float*)d_in[4];
    const float* W2rel  = (const float*)d_in[5];
    const float* b2     = (const float*)d_in[6];
    const float* W2root = (const float*)d_in[7];
    float* out = (float*)d_out;

    int n = in_sizes[0] / DD;
    int E = in_sizes[1] / 2;
    const int* src = eidx;
    const int* dstp = eidx + E;

    char* ws = (char*)d_ws;
    size_t off = 0;
    auto alloc = [&](size_t bytes) -> char* {
        char* p = ws + off;
        off = (off + bytes + 255) & ~(size_t)255;
        return p;
    };
    float* y      = (float*)alloc((size_t)n * LL * 4);
    float* z      = (float*)alloc((size_t)n * LL * 4);
    int*   deg    = (int*)  alloc((size_t)n * 4);
    int*   rowptr = (int*)  alloc((size_t)(n + 1) * 4);
    int*   cursor = (int*)  alloc((size_t)n * 4);
    int*   csr    = (int*)  alloc((size_t)E * 4);
    float* s      = (float*)alloc((size_t)n * 4);
    float* t      = (float*)alloc((size_t)n * 4);
    float* g      = (float*)alloc((size_t)n * 4);
    int NB = (n + 1023) / 1024;
    int* blocksum = (int*)alloc((size_t)NB * 4);
    int* blockoff = (int*)alloc((size_t)NB * 4);
    float* pmax   = (float*)alloc(256 * 4);
    float* scalars= (float*)alloc(2 * 4);
    (void)ws_size; (void)n_in;

    hipMemsetAsync(deg, 0, (size_t)n * 4, stream);
    hipMemsetAsync(scalars, 0, 8, stream);
    hipMemsetAsync(d_out, 0, (size_t)out_size * 4, stream);

    k_deg<<<(E + 255) / 256, 256, 0, stream>>>(dstp, deg, E);
    k1_gemm<<<(n + 31) / 32, 256, 0, stream>>>(x, W1rel, W1root, y, z, n);
    p1_blocksum<<<NB, 1024, 0, stream>>>(deg, blocksum, n);
    p2_scan_blocks<<<1, 64, 0, stream>>>(blocksum, blockoff, NB);
    p3_scan<<<NB, 1024, 0, stream>>>(deg, blockoff, rowptr, cursor, n);
    k2c_scatter<<<(E + 255) / 256, 256, 0, stream>>>(src, dstp, cursor, csr, E);
    k3_agg<<<(n + 3) / 4, 256, 0, stream>>>(y, z, rowptr, csr, b1, W2rel, W2root, s, t, n);
    k5_gate<<<(n + 255) / 256, 256, 0, stream>>>(s, t, rowptr, csr, b2, g, n);
    k6_max<<<256, 256, 0, stream>>>(g, pmax, n);
    k6_maxfin<<<1, 256, 0, stream>>>(pmax, scalars);
    k6_sumexp<<<256, 256, 0, stream>>>(g, scalars, n);
    k6_out<<<512, 256, 0, stream>>>(x, g, scalars, out, n);
}